// Round 5
// baseline (1809.965 us; speedup 1.0000x reference)
//
#include <hip/hip_runtime.h>

#define NN 100000
#define NE 1600000
#define NBUCK 782   // ceil(NN/128), bucket = dst >> 7
#define PCHUNK 8192 // edges per k_pairs block

struct alignas(8) US4 { unsigned short x, y, z, w; };

__device__ __forceinline__ float bfu(unsigned int hw) { return __uint_as_float(hw << 16); }
__device__ __forceinline__ unsigned short f2bf(float f) {
    unsigned int u = __float_as_uint(f);
    return (unsigned short)((u + 0x7fffu + ((u >> 16) & 1u)) >> 16);
}

// ---------------- build: bucket-ordered packed edge list ----------------

__global__ __launch_bounds__(256) void k_hist(const int* __restrict__ src,
                                              const int* __restrict__ dst,
                                              int* __restrict__ cnt_out,
                                              int* __restrict__ bucket_cnt) {
    __shared__ int hist[NBUCK];
    int tid = threadIdx.x;
    for (int i = tid; i < NBUCK; i += 256) hist[i] = 0;
    __syncthreads();
    int stride = gridDim.x * 256;
    for (int e = blockIdx.x * 256 + tid; e < NE; e += stride) {
        atomicAdd(&hist[dst[e] >> 7], 1);
        atomicAdd(&cnt_out[src[e]], 1);
    }
    __syncthreads();
    for (int i = tid; i < NBUCK; i += 256)
        if (hist[i]) atomicAdd(&bucket_cnt[i], hist[i]);
}

__global__ __launch_bounds__(1024) void k_bscan(const int* __restrict__ bucket_cnt,
                                                int* __restrict__ bucket_base,
                                                int* __restrict__ bucket_cursor) {
    __shared__ int tmp[1024];
    int t = threadIdx.x;
    int v = (t < NBUCK) ? bucket_cnt[t] : 0;
    tmp[t] = v;
    __syncthreads();
    for (int off = 1; off < 1024; off <<= 1) {
        int u = (t >= off) ? tmp[t - off] : 0;
        __syncthreads();
        tmp[t] += u;
        __syncthreads();
    }
    int excl = tmp[t] - v;
    if (t < NBUCK) {
        bucket_base[t] = excl;
        bucket_cursor[t] = excl;
    }
    if (t == 0) bucket_base[NBUCK] = NE;
}

// LDS-binned scatter: bulk range reservation per (block,bucket), then packed
// (src<<7 | dst&127) words written into per-block contiguous runs.
__global__ __launch_bounds__(256) void k_pairs(const int* __restrict__ src,
                                               const int* __restrict__ dst,
                                               int* __restrict__ bucket_cursor,
                                               int* __restrict__ E2) {
    __shared__ int hist[NBUCK], gbase[NBUCK];
    int tid = threadIdx.x;
    for (int i = tid; i < NBUCK; i += 256) hist[i] = 0;
    __syncthreads();
    int base = blockIdx.x * PCHUNK;
#pragma unroll
    for (int i = 0; i < PCHUNK / 256; ++i) {
        int e = base + i * 256 + tid;
        if (e < NE) atomicAdd(&hist[dst[e] >> 7], 1);
    }
    __syncthreads();
    for (int i = tid; i < NBUCK; i += 256) {
        int h = hist[i];
        if (h) gbase[i] = atomicAdd(&bucket_cursor[i], h);
        hist[i] = 0;
    }
    __syncthreads();
#pragma unroll
    for (int i = 0; i < PCHUNK / 256; ++i) {
        int e = base + i * 256 + tid;
        if (e < NE) {
            int d = dst[e];
            int b = d >> 7;
            int pos = atomicAdd(&hist[b], 1);
            E2[gbase[b] + pos] = (src[e] << 7) | (d & 127);
        }
    }
}

__global__ __launch_bounds__(256) void k_rout(const int* __restrict__ cnt_out,
                                              float* __restrict__ r_out) {
    int t = blockIdx.x * 256 + threadIdx.x;
    if (t < NN) r_out[t] = rsqrtf((float)max(cnt_out[t], 1));
}

// ---------------- dense GEMMs ----------------

// A(bf16) = (x @ W0) * r_out.  64 nodes/block, thread = 4m x 4n, K=128 in two halves.
__global__ __launch_bounds__(256) void k_gemm0(const float* __restrict__ x,
                                               const float* __restrict__ W0,
                                               const float* __restrict__ r_out,
                                               unsigned short* __restrict__ A) {
    __shared__ float xl[64 * 129];
    __shared__ float wl[64 * 64];
    int tid = threadIdx.x;
    int m0 = blockIdx.x * 64;
#pragma unroll
    for (int i = 0; i < 8; ++i) {
        int idx = i * 256 + tid;
        int m = idx >> 5, kc = idx & 31;
        int gm = min(m0 + m, NN - 1);
        float4 v = *(const float4*)&x[(size_t)gm * 128 + kc * 4];
        float* p = &xl[m * 129 + kc * 4];
        p[0] = v.x; p[1] = v.y; p[2] = v.z; p[3] = v.w;
    }
    int tn = tid & 15, tm = tid >> 4;
    float acc[4][4] = {};
    const float4* W4 = (const float4*)W0;
    float4* wl4 = (float4*)wl;
    for (int h = 0; h < 2; ++h) {
        __syncthreads();
#pragma unroll
        for (int i = 0; i < 4; ++i) wl4[i * 256 + tid] = W4[h * 1024 + i * 256 + tid];
        __syncthreads();
#pragma unroll 4
        for (int k = 0; k < 64; ++k) {
            int kk = h * 64 + k;
            float4 wv = *(const float4*)&wl[k * 64 + tn * 4];
            float xv[4];
#pragma unroll
            for (int i = 0; i < 4; ++i) xv[i] = xl[(tm * 4 + i) * 129 + kk];
#pragma unroll
            for (int i = 0; i < 4; ++i) {
                acc[i][0] = fmaf(xv[i], wv.x, acc[i][0]);
                acc[i][1] = fmaf(xv[i], wv.y, acc[i][1]);
                acc[i][2] = fmaf(xv[i], wv.z, acc[i][2]);
                acc[i][3] = fmaf(xv[i], wv.w, acc[i][3]);
            }
        }
    }
#pragma unroll
    for (int i = 0; i < 4; ++i) {
        int m = m0 + tm * 4 + i;
        if (m < NN) {
            float ro = r_out[m];
            US4 o = {f2bf(acc[i][0] * ro), f2bf(acc[i][1] * ro),
                     f2bf(acc[i][2] * ro), f2bf(acc[i][3] * ro)};
            *(US4*)&A[(size_t)m * 64 + tn * 4] = o;
        }
    }
}

// C = (relu(G @ W1 + b1) @ W2) * r_out.  G is bf16.  64 nodes/block.
__global__ __launch_bounds__(256) void k_mlp(const unsigned short* __restrict__ G,
                                             const float* __restrict__ W1,
                                             const float* __restrict__ b1,
                                             const float* __restrict__ W2,
                                             const float* __restrict__ r_out,
                                             float* __restrict__ C) {
    __shared__ float gl[64 * 65];
    __shared__ float w1l[64 * 64];
    __shared__ float w2l[64 * 16];
    int tid = threadIdx.x;
    int m0 = blockIdx.x * 64;
#pragma unroll
    for (int i = 0; i < 2; ++i) {
        int idx = i * 256 + tid;       // 512 chunks of 8 bf16
        int m = idx >> 3, c8 = idx & 7;
        int gm = min(m0 + m, NN - 1);
        uint4 u = *(const uint4*)&G[(size_t)gm * 64 + c8 * 8];
        float* p = &gl[m * 65 + c8 * 8];
        p[0] = bfu(u.x & 0xffffu); p[1] = bfu(u.x >> 16);
        p[2] = bfu(u.y & 0xffffu); p[3] = bfu(u.y >> 16);
        p[4] = bfu(u.z & 0xffffu); p[5] = bfu(u.z >> 16);
        p[6] = bfu(u.w & 0xffffu); p[7] = bfu(u.w >> 16);
    }
    float4* w1l4 = (float4*)w1l;
    const float4* W1_4 = (const float4*)W1;
#pragma unroll
    for (int i = 0; i < 4; ++i) w1l4[i * 256 + tid] = W1_4[i * 256 + tid];
    ((float4*)w2l)[tid] = ((const float4*)W2)[tid];
    __syncthreads();
    int tn = tid & 15, tm = tid >> 4;
    float acc[4][4] = {};
#pragma unroll 4
    for (int k = 0; k < 64; ++k) {
        float4 wv = *(const float4*)&w1l[k * 64 + tn * 4];
        float xv[4];
#pragma unroll
        for (int i = 0; i < 4; ++i) xv[i] = gl[(tm * 4 + i) * 65 + k];
#pragma unroll
        for (int i = 0; i < 4; ++i) {
            acc[i][0] = fmaf(xv[i], wv.x, acc[i][0]);
            acc[i][1] = fmaf(xv[i], wv.y, acc[i][1]);
            acc[i][2] = fmaf(xv[i], wv.z, acc[i][2]);
            acc[i][3] = fmaf(xv[i], wv.w, acc[i][3]);
        }
    }
    float4 bb = *(const float4*)&b1[tn * 4];
    __syncthreads();
#pragma unroll
    for (int i = 0; i < 4; ++i) {
        gl[(tm * 4 + i) * 65 + tn * 4 + 0] = fmaxf(acc[i][0] + bb.x, 0.f);
        gl[(tm * 4 + i) * 65 + tn * 4 + 1] = fmaxf(acc[i][1] + bb.y, 0.f);
        gl[(tm * 4 + i) * 65 + tn * 4 + 2] = fmaxf(acc[i][2] + bb.z, 0.f);
        gl[(tm * 4 + i) * 65 + tn * 4 + 3] = fmaxf(acc[i][3] + bb.w, 0.f);
    }
    __syncthreads();
    int m = tid >> 2, n0 = (tid & 3) * 4;
    float a2[4] = {};
#pragma unroll 8
    for (int k = 0; k < 64; ++k) {
        float zv = gl[m * 65 + k];
        float4 wv = *(const float4*)&w2l[k * 16 + n0];
        a2[0] = fmaf(zv, wv.x, a2[0]);
        a2[1] = fmaf(zv, wv.y, a2[1]);
        a2[2] = fmaf(zv, wv.z, a2[2]);
        a2[3] = fmaf(zv, wv.w, a2[3]);
    }
    int node = m0 + m;
    if (node < NN) {
        float ro = r_out[node];
        float4 o = {a2[0] * ro, a2[1] * ro, a2[2] * ro, a2[3] * ro};
        *(float4*)&C[(size_t)node * 16 + n0] = o;
    }
}

// ---------------- bucket-local LDS aggregation ----------------

// One block per 128-node dst bucket: accumulate bf16 h[src] rows into 32KB LDS
// acc via ds_add_f32, count in-degrees in LDS, fused epilogue.
// MODE 0: out = bf16(relu(acc*r_in + b0)*r_out)     (layer0 -> B)
// MODE 1: out = bf16(acc*r_in)                      (layer1 -> G)
template <int MODE>
__global__ __launch_bounds__(256) void k_agg64(const int* __restrict__ E2,
                                               const int* __restrict__ bucket_base,
                                               const unsigned short* __restrict__ h,
                                               const float* __restrict__ r_out,
                                               const float* __restrict__ bias,
                                               unsigned short* __restrict__ outb) {
    __shared__ float acc[128 * 64];  // 32 KB
    __shared__ float degs[128];
    int tid = threadIdx.x;
    float4* a4 = (float4*)acc;
    float4 z4 = {0, 0, 0, 0};
#pragma unroll
    for (int i = 0; i < 8; ++i) a4[i * 256 + tid] = z4;
    if (tid < 128) degs[tid] = 0.f;
    __syncthreads();
    int b = blockIdx.x;
    int base = bucket_base[b], end = bucket_base[b + 1];
    int f = tid & 15;
    for (int i0 = base + (tid >> 4); i0 < end; i0 += 32) {
        int i1 = i0 + 16;
        int eA = E2[i0];
        int sA = eA >> 7, dA = eA & 127;
        uint2 uA = *(const uint2*)(h + (size_t)sA * 64 + f * 4);
        bool hasB = i1 < end;
        int eB = hasB ? E2[i1] : eA;
        int sB = eB >> 7, dB = eB & 127;
        uint2 uB = *(const uint2*)(h + (size_t)sB * 64 + f * 4);
        float* pa = &acc[dA * 64 + f * 4];
        atomicAdd(pa + 0, bfu(uA.x & 0xffffu));
        atomicAdd(pa + 1, bfu(uA.x >> 16));
        atomicAdd(pa + 2, bfu(uA.y & 0xffffu));
        atomicAdd(pa + 3, bfu(uA.y >> 16));
        if (f == 0) atomicAdd(&degs[dA], 1.f);
        if (hasB) {
            float* pb = &acc[dB * 64 + f * 4];
            atomicAdd(pb + 0, bfu(uB.x & 0xffffu));
            atomicAdd(pb + 1, bfu(uB.x >> 16));
            atomicAdd(pb + 2, bfu(uB.y & 0xffffu));
            atomicAdd(pb + 3, bfu(uB.y >> 16));
            if (f == 0) atomicAdd(&degs[dB], 1.f);
        }
    }
    __syncthreads();
    for (int idx = tid; idx < 2048; idx += 256) {
        int r = idx >> 4, f4 = (idx & 15) * 4;
        int node = b * 128 + r;
        if (node >= NN) continue;
        float ri = rsqrtf(fmaxf(degs[r], 1.f));
        float4 v = *(float4*)&acc[r * 64 + f4];
        US4 o;
        if (MODE == 0) {
            float ro = r_out[node];
            float4 bb = *(const float4*)&bias[f4];
            o.x = f2bf(fmaxf(fmaf(v.x, ri, bb.x), 0.f) * ro);
            o.y = f2bf(fmaxf(fmaf(v.y, ri, bb.y), 0.f) * ro);
            o.z = f2bf(fmaxf(fmaf(v.z, ri, bb.z), 0.f) * ro);
            o.w = f2bf(fmaxf(fmaf(v.w, ri, bb.w), 0.f) * ro);
        } else {
            o.x = f2bf(v.x * ri); o.y = f2bf(v.y * ri);
            o.z = f2bf(v.z * ri); o.w = f2bf(v.w * ri);
        }
        *(US4*)&outb[(size_t)node * 64 + f4] = o;
    }
}

// d=16 fp32 variant: out = acc*r_in + b2 (final layer, writes d_out)
__global__ __launch_bounds__(256) void k_agg16(const int* __restrict__ E2,
                                               const int* __restrict__ bucket_base,
                                               const float* __restrict__ C,
                                               const float* __restrict__ b2,
                                               float* __restrict__ out) {
    __shared__ float acc[128 * 16];  // 8 KB
    __shared__ float degs[128];
    int tid = threadIdx.x;
    float4* a4 = (float4*)acc;
    float4 z4 = {0, 0, 0, 0};
#pragma unroll
    for (int i = 0; i < 2; ++i) a4[i * 256 + tid] = z4;
    if (tid < 128) degs[tid] = 0.f;
    __syncthreads();
    int b = blockIdx.x;
    int base = bucket_base[b], end = bucket_base[b + 1];
    int f = tid & 3;
    for (int i0 = base + (tid >> 2); i0 < end; i0 += 128) {
        int i1 = i0 + 64;
        int eA = E2[i0];
        int sA = eA >> 7, dA = eA & 127;
        float4 vA = *(const float4*)(C + (size_t)sA * 16 + f * 4);
        bool hasB = i1 < end;
        int eB = hasB ? E2[i1] : eA;
        int sB = eB >> 7, dB = eB & 127;
        float4 vB = *(const float4*)(C + (size_t)sB * 16 + f * 4);
        float* pa = &acc[dA * 16 + f * 4];
        atomicAdd(pa + 0, vA.x); atomicAdd(pa + 1, vA.y);
        atomicAdd(pa + 2, vA.z); atomicAdd(pa + 3, vA.w);
        if (f == 0) atomicAdd(&degs[dA], 1.f);
        if (hasB) {
            float* pb = &acc[dB * 16 + f * 4];
            atomicAdd(pb + 0, vB.x); atomicAdd(pb + 1, vB.y);
            atomicAdd(pb + 2, vB.z); atomicAdd(pb + 3, vB.w);
            if (f == 0) atomicAdd(&degs[dB], 1.f);
        }
    }
    __syncthreads();
    for (int idx = tid; idx < 512; idx += 256) {
        int r = idx >> 2, f4 = (idx & 3) * 4;
        int node = b * 128 + r;
        if (node >= NN) continue;
        float ri = rsqrtf(fmaxf(degs[r], 1.f));
        float4 v = *(float4*)&acc[r * 16 + f4];
        float4 bb = *(const float4*)&b2[f4];
        float4 o = {fmaf(v.x, ri, bb.x), fmaf(v.y, ri, bb.y),
                    fmaf(v.z, ri, bb.z), fmaf(v.w, ri, bb.w)};
        *(float4*)&out[(size_t)node * 16 + f4] = o;
    }
}

extern "C" void kernel_launch(void* const* d_in, const int* in_sizes, int n_in,
                              void* d_out, int out_size, void* d_ws, size_t ws_size,
                              hipStream_t stream) {
    const float* feats = (const float*)d_in[0];
    const int* src = (const int*)d_in[1];
    const int* dst = (const int*)d_in[2];
    const float* W0 = (const float*)d_in[3];
    const float* b0 = (const float*)d_in[4];
    const float* W1 = (const float*)d_in[5];
    const float* b1 = (const float*)d_in[6];
    const float* W2 = (const float*)d_in[7];
    const float* b2 = (const float*)d_in[8];
    float* out = (float*)d_out;

    // ws (float units): r_out[NN] | E2[NE] | A/G[32NN] (bf16 64/row; transients
    // cnt_out+bucket_cnt alias head) | B[32NN] (bf16) | C[16NN] f32 | bases
    float* ws = (float*)d_ws;
    float* r_out = ws;
    int* E2 = (int*)(ws + NN);
    unsigned short* A = (unsigned short*)(ws + NN + NE);
    unsigned short* G = A;  // A dead after k_agg64<0>
    unsigned short* B = (unsigned short*)(ws + NN + NE + (size_t)32 * NN);
    float* C = ws + NN + NE + (size_t)64 * NN;
    int* bucket_base = (int*)(C + (size_t)16 * NN);  // NBUCK+1
    int* bucket_cursor = bucket_base + NBUCK + 1;    // NBUCK
    int* cnt_out = (int*)A;                          // transient
    int* bucket_cnt = cnt_out + NN;                  // transient

    hipMemsetAsync(cnt_out, 0, (NN + NBUCK) * sizeof(int), stream);
    k_hist<<<256, 256, 0, stream>>>(src, dst, cnt_out, bucket_cnt);
    k_bscan<<<1, 1024, 0, stream>>>(bucket_cnt, bucket_base, bucket_cursor);
    k_pairs<<<(NE + PCHUNK - 1) / PCHUNK, 256, 0, stream>>>(src, dst, bucket_cursor, E2);
    k_rout<<<(NN + 255) / 256, 256, 0, stream>>>(cnt_out, r_out);

    // layer 0
    k_gemm0<<<(NN + 63) / 64, 256, 0, stream>>>(feats, W0, r_out, A);
    k_agg64<0><<<NBUCK, 256, 0, stream>>>(E2, bucket_base, A, r_out, b0, B);

    // layer 1 (+ layer2 pre-GEMM)
    k_agg64<1><<<NBUCK, 256, 0, stream>>>(E2, bucket_base, B, nullptr, nullptr, G);
    k_mlp<<<(NN + 63) / 64, 256, 0, stream>>>(G, W1, b1, W2, r_out, C);

    // layer 2
    k_agg16<<<NBUCK, 256, 0, stream>>>(E2, bucket_base, C, b2, out);
}

// Round 6
// 405.101 us; speedup vs baseline: 4.4679x; 4.4679x over previous
//
#include <hip/hip_runtime.h>

#define NN 100000
#define NE 1600000
#define NBUCK 782   // ceil(NN/128), bucket = dst >> 7
#define PCHUNK 8192 // edges per k_pairs block

struct alignas(8) US4 { unsigned short x, y, z, w; };

__device__ __forceinline__ float bfu(unsigned int hw) { return __uint_as_float(hw << 16); }
__device__ __forceinline__ unsigned short f2bf(float f) {
    unsigned int u = __float_as_uint(f);
    return (unsigned short)((u + 0x7fffu + ((u >> 16) & 1u)) >> 16);
}

// ---------------- build: bucket-ordered packed edges -> per-node CSR ----------------

__global__ __launch_bounds__(256) void k_hist(const int* __restrict__ src,
                                              const int* __restrict__ dst,
                                              int* __restrict__ cnt_out,
                                              int* __restrict__ bucket_cnt) {
    __shared__ int hist[NBUCK];
    int tid = threadIdx.x;
    for (int i = tid; i < NBUCK; i += 256) hist[i] = 0;
    __syncthreads();
    int stride = gridDim.x * 256;
    for (int e = blockIdx.x * 256 + tid; e < NE; e += stride) {
        atomicAdd(&hist[dst[e] >> 7], 1);
        atomicAdd(&cnt_out[src[e]], 1);
    }
    __syncthreads();
    for (int i = tid; i < NBUCK; i += 256)
        if (hist[i]) atomicAdd(&bucket_cnt[i], hist[i]);
}

__global__ __launch_bounds__(1024) void k_bscan(const int* __restrict__ bucket_cnt,
                                                int* __restrict__ bucket_base,
                                                int* __restrict__ bucket_cursor) {
    __shared__ int tmp[1024];
    int t = threadIdx.x;
    int v = (t < NBUCK) ? bucket_cnt[t] : 0;
    tmp[t] = v;
    __syncthreads();
    for (int off = 1; off < 1024; off <<= 1) {
        int u = (t >= off) ? tmp[t - off] : 0;
        __syncthreads();
        tmp[t] += u;
        __syncthreads();
    }
    int excl = tmp[t] - v;
    if (t < NBUCK) {
        bucket_base[t] = excl;
        bucket_cursor[t] = excl;
    }
    if (t == 0) bucket_base[NBUCK] = NE;
}

// LDS-binned scatter: bulk range reservation per (block,bucket), then packed
// (src<<7 | dst&127) words written into per-block contiguous runs.
__global__ __launch_bounds__(256) void k_pairs(const int* __restrict__ src,
                                               const int* __restrict__ dst,
                                               int* __restrict__ bucket_cursor,
                                               int* __restrict__ E2) {
    __shared__ int hist[NBUCK], gbase[NBUCK];
    int tid = threadIdx.x;
    for (int i = tid; i < NBUCK; i += 256) hist[i] = 0;
    __syncthreads();
    int base = blockIdx.x * PCHUNK;
#pragma unroll
    for (int i = 0; i < PCHUNK / 256; ++i) {
        int e = base + i * 256 + tid;
        if (e < NE) atomicAdd(&hist[dst[e] >> 7], 1);
    }
    __syncthreads();
    for (int i = tid; i < NBUCK; i += 256) {
        int h = hist[i];
        if (h) gbase[i] = atomicAdd(&bucket_cursor[i], h);
        hist[i] = 0;
    }
    __syncthreads();
#pragma unroll
    for (int i = 0; i < PCHUNK / 256; ++i) {
        int e = base + i * 256 + tid;
        if (e < NE) {
            int d = dst[e];
            int b = d >> 7;
            int pos = atomicAdd(&hist[b], 1);
            E2[gbase[b] + pos] = (src[e] << 7) | (d & 127);
        }
    }
}

// per-bucket: LDS count+scan+cursor -> row_start, r_in, csr (block-local writes)
__global__ __launch_bounds__(256) void k_bcsr(const int* __restrict__ E2,
                                              const int* __restrict__ bucket_base,
                                              int* __restrict__ row_start,
                                              float* __restrict__ r_in,
                                              int* __restrict__ csr) {
    __shared__ int cnt[128], cur[128];
    int tid = threadIdx.x;
    int b = blockIdx.x;
    int base = bucket_base[b], end = bucket_base[b + 1];
    if (tid < 128) cnt[tid] = 0;
    __syncthreads();
    for (int i = base + tid; i < end; i += 256) atomicAdd(&cnt[E2[i] & 127], 1);
    __syncthreads();
    int v = (tid < 128) ? cnt[tid] : 0;
    for (int off = 1; off < 128; off <<= 1) {
        int u = (tid >= off && tid < 128) ? cnt[tid - off] : 0;
        __syncthreads();
        if (tid < 128) cnt[tid] += u;
        __syncthreads();
    }
    if (tid < 128) {
        int excl = cnt[tid] - v;  // exclusive scan within bucket
        cur[tid] = excl;
        int node = b * 128 + tid;
        if (node <= NN) row_start[node] = base + excl;
        if (node < NN) r_in[node] = rsqrtf((float)max(v, 1));
    }
    __syncthreads();
    for (int i = base + tid; i < end; i += 256) {
        int e = E2[i];
        int pos = atomicAdd(&cur[e & 127], 1);
        csr[base + pos] = e >> 7;
    }
}

__global__ __launch_bounds__(256) void k_rout(const int* __restrict__ cnt_out,
                                              float* __restrict__ r_out) {
    int t = blockIdx.x * 256 + threadIdx.x;
    if (t < NN) r_out[t] = rsqrtf((float)max(cnt_out[t], 1));
}

// ---------------- dense GEMMs ----------------

// A(bf16) = (x @ W0) * r_out.  64 nodes/block, thread = 4m x 4n, K=128 in two halves.
__global__ __launch_bounds__(256) void k_gemm0(const float* __restrict__ x,
                                               const float* __restrict__ W0,
                                               const float* __restrict__ r_out,
                                               unsigned short* __restrict__ A) {
    __shared__ float xl[64 * 129];
    __shared__ float wl[64 * 64];
    int tid = threadIdx.x;
    int m0 = blockIdx.x * 64;
#pragma unroll
    for (int i = 0; i < 8; ++i) {
        int idx = i * 256 + tid;
        int m = idx >> 5, kc = idx & 31;
        int gm = min(m0 + m, NN - 1);
        float4 v = *(const float4*)&x[(size_t)gm * 128 + kc * 4];
        float* p = &xl[m * 129 + kc * 4];
        p[0] = v.x; p[1] = v.y; p[2] = v.z; p[3] = v.w;
    }
    int tn = tid & 15, tm = tid >> 4;
    float acc[4][4] = {};
    const float4* W4 = (const float4*)W0;
    float4* wl4 = (float4*)wl;
    for (int h = 0; h < 2; ++h) {
        __syncthreads();
#pragma unroll
        for (int i = 0; i < 4; ++i) wl4[i * 256 + tid] = W4[h * 1024 + i * 256 + tid];
        __syncthreads();
#pragma unroll 4
        for (int k = 0; k < 64; ++k) {
            int kk = h * 64 + k;
            float4 wv = *(const float4*)&wl[k * 64 + tn * 4];
            float xv[4];
#pragma unroll
            for (int i = 0; i < 4; ++i) xv[i] = xl[(tm * 4 + i) * 129 + kk];
#pragma unroll
            for (int i = 0; i < 4; ++i) {
                acc[i][0] = fmaf(xv[i], wv.x, acc[i][0]);
                acc[i][1] = fmaf(xv[i], wv.y, acc[i][1]);
                acc[i][2] = fmaf(xv[i], wv.z, acc[i][2]);
                acc[i][3] = fmaf(xv[i], wv.w, acc[i][3]);
            }
        }
    }
#pragma unroll
    for (int i = 0; i < 4; ++i) {
        int m = m0 + tm * 4 + i;
        if (m < NN) {
            float ro = r_out[m];
            US4 o = {f2bf(acc[i][0] * ro), f2bf(acc[i][1] * ro),
                     f2bf(acc[i][2] * ro), f2bf(acc[i][3] * ro)};
            *(US4*)&A[(size_t)m * 64 + tn * 4] = o;
        }
    }
}

// C = (relu(G @ W1 + b1) @ W2) * r_out.  G is bf16.  64 nodes/block.
__global__ __launch_bounds__(256) void k_mlp(const unsigned short* __restrict__ G,
                                             const float* __restrict__ W1,
                                             const float* __restrict__ b1,
                                             const float* __restrict__ W2,
                                             const float* __restrict__ r_out,
                                             float* __restrict__ C) {
    __shared__ float gl[64 * 65];
    __shared__ float w1l[64 * 64];
    __shared__ float w2l[64 * 16];
    int tid = threadIdx.x;
    int m0 = blockIdx.x * 64;
#pragma unroll
    for (int i = 0; i < 2; ++i) {
        int idx = i * 256 + tid;  // 512 chunks of 8 bf16
        int m = idx >> 3, c8 = idx & 7;
        int gm = min(m0 + m, NN - 1);
        uint4 u = *(const uint4*)&G[(size_t)gm * 64 + c8 * 8];
        float* p = &gl[m * 65 + c8 * 8];
        p[0] = bfu(u.x & 0xffffu); p[1] = bfu(u.x >> 16);
        p[2] = bfu(u.y & 0xffffu); p[3] = bfu(u.y >> 16);
        p[4] = bfu(u.z & 0xffffu); p[5] = bfu(u.z >> 16);
        p[6] = bfu(u.w & 0xffffu); p[7] = bfu(u.w >> 16);
    }
    float4* w1l4 = (float4*)w1l;
    const float4* W1_4 = (const float4*)W1;
#pragma unroll
    for (int i = 0; i < 4; ++i) w1l4[i * 256 + tid] = W1_4[i * 256 + tid];
    ((float4*)w2l)[tid] = ((const float4*)W2)[tid];
    __syncthreads();
    int tn = tid & 15, tm = tid >> 4;
    float acc[4][4] = {};
#pragma unroll 4
    for (int k = 0; k < 64; ++k) {
        float4 wv = *(const float4*)&w1l[k * 64 + tn * 4];
        float xv[4];
#pragma unroll
        for (int i = 0; i < 4; ++i) xv[i] = gl[(tm * 4 + i) * 65 + k];
#pragma unroll
        for (int i = 0; i < 4; ++i) {
            acc[i][0] = fmaf(xv[i], wv.x, acc[i][0]);
            acc[i][1] = fmaf(xv[i], wv.y, acc[i][1]);
            acc[i][2] = fmaf(xv[i], wv.z, acc[i][2]);
            acc[i][3] = fmaf(xv[i], wv.w, acc[i][3]);
        }
    }
    float4 bb = *(const float4*)&b1[tn * 4];
    __syncthreads();
#pragma unroll
    for (int i = 0; i < 4; ++i) {
        gl[(tm * 4 + i) * 65 + tn * 4 + 0] = fmaxf(acc[i][0] + bb.x, 0.f);
        gl[(tm * 4 + i) * 65 + tn * 4 + 1] = fmaxf(acc[i][1] + bb.y, 0.f);
        gl[(tm * 4 + i) * 65 + tn * 4 + 2] = fmaxf(acc[i][2] + bb.z, 0.f);
        gl[(tm * 4 + i) * 65 + tn * 4 + 3] = fmaxf(acc[i][3] + bb.w, 0.f);
    }
    __syncthreads();
    int m = tid >> 2, n0 = (tid & 3) * 4;
    float a2[4] = {};
#pragma unroll 8
    for (int k = 0; k < 64; ++k) {
        float zv = gl[m * 65 + k];
        float4 wv = *(const float4*)&w2l[k * 16 + n0];
        a2[0] = fmaf(zv, wv.x, a2[0]);
        a2[1] = fmaf(zv, wv.y, a2[1]);
        a2[2] = fmaf(zv, wv.z, a2[2]);
        a2[3] = fmaf(zv, wv.w, a2[3]);
    }
    int node = m0 + m;
    if (node < NN) {
        float ro = r_out[node];
        float4 o = {a2[0] * ro, a2[1] * ro, a2[2] * ro, a2[3] * ro};
        *(float4*)&C[(size_t)node * 16 + n0] = o;
    }
}

// ---------------- gathers (register-accumulate, per-node wave) ----------------

// d=64 bf16 gather, 1 node/wave, 8 edges in flight (16 lanes x 8B each).
// MODE 0: o16 = bf16(relu(agg*r_in + bias)*r_out)   (layer0 -> B)
// MODE 1: o16 = bf16(agg*r_in)                      (layer1 -> G, feeds k_mlp)
template <int MODE>
__global__ __launch_bounds__(256) void k_gather64(const int* __restrict__ row_start,
                                                  const int* __restrict__ csr,
                                                  const unsigned short* __restrict__ h,
                                                  const float* __restrict__ r_in,
                                                  const float* __restrict__ r_out,
                                                  const float* __restrict__ bias,
                                                  unsigned short* __restrict__ o16) {
    int tid = threadIdx.x;
    int wave = tid >> 6, lane = tid & 63;
    int n = blockIdx.x * 4 + wave;
    int jb = row_start[n], je = row_start[n + 1];
    int g = lane >> 4, f = lane & 15;
    float4 a0 = {0, 0, 0, 0}, a1 = {0, 0, 0, 0};
    for (int j = jb; j < je; j += 8) {
        int i0 = j + g, i1 = i0 + 4;
        int s0 = csr[min(i0, je - 1)];
        int s1 = csr[min(i1, je - 1)];
        uint2 u0 = *(const uint2*)(h + (size_t)s0 * 64 + f * 4);
        uint2 u1 = *(const uint2*)(h + (size_t)s1 * 64 + f * 4);
        float w0 = (i0 < je) ? 1.f : 0.f;
        float w1 = (i1 < je) ? 1.f : 0.f;
        a0.x = fmaf(w0, bfu(u0.x & 0xffffu), a0.x);
        a0.y = fmaf(w0, bfu(u0.x >> 16), a0.y);
        a0.z = fmaf(w0, bfu(u0.y & 0xffffu), a0.z);
        a0.w = fmaf(w0, bfu(u0.y >> 16), a0.w);
        a1.x = fmaf(w1, bfu(u1.x & 0xffffu), a1.x);
        a1.y = fmaf(w1, bfu(u1.x >> 16), a1.y);
        a1.z = fmaf(w1, bfu(u1.y & 0xffffu), a1.z);
        a1.w = fmaf(w1, bfu(u1.y >> 16), a1.w);
    }
    a0.x += a1.x; a0.y += a1.y; a0.z += a1.z; a0.w += a1.w;
    a0.x += __shfl_xor(a0.x, 16); a0.y += __shfl_xor(a0.y, 16);
    a0.z += __shfl_xor(a0.z, 16); a0.w += __shfl_xor(a0.w, 16);
    a0.x += __shfl_xor(a0.x, 32); a0.y += __shfl_xor(a0.y, 32);
    a0.z += __shfl_xor(a0.z, 32); a0.w += __shfl_xor(a0.w, 32);
    if (g == 0) {
        float ri = r_in[n];
        US4 o;
        if (MODE == 0) {
            float ro = r_out[n];
            float4 bb = *(const float4*)&bias[f * 4];
            o.x = f2bf(fmaxf(fmaf(a0.x, ri, bb.x), 0.f) * ro);
            o.y = f2bf(fmaxf(fmaf(a0.y, ri, bb.y), 0.f) * ro);
            o.z = f2bf(fmaxf(fmaf(a0.z, ri, bb.z), 0.f) * ro);
            o.w = f2bf(fmaxf(fmaf(a0.w, ri, bb.w), 0.f) * ro);
        } else {
            o.x = f2bf(a0.x * ri); o.y = f2bf(a0.y * ri);
            o.z = f2bf(a0.z * ri); o.w = f2bf(a0.w * ri);
        }
        *(US4*)&o16[(size_t)n * 64 + f * 4] = o;
    }
}

// d=16 fp32 gather: out = agg*r_in + b2
__global__ __launch_bounds__(256) void k_gather16(const int* __restrict__ row_start,
                                                  const int* __restrict__ csr,
                                                  const float* __restrict__ C,
                                                  const float* __restrict__ r_in,
                                                  const float* __restrict__ b2,
                                                  float* __restrict__ out) {
    int tid = threadIdx.x;
    int wave = tid >> 6, lane = tid & 63;
    int n = blockIdx.x * 4 + wave;
    int jb = row_start[n], je = row_start[n + 1];
    int g = lane >> 2, f = lane & 3;
    float4 acc = {0, 0, 0, 0};
    for (int j = jb; j < je; j += 16) {
        int i0 = j + g;
        int s = csr[min(i0, je - 1)];
        float4 v = *(const float4*)&C[(size_t)s * 16 + f * 4];
        float w = (i0 < je) ? 1.f : 0.f;
        acc.x = fmaf(w, v.x, acc.x); acc.y = fmaf(w, v.y, acc.y);
        acc.z = fmaf(w, v.z, acc.z); acc.w = fmaf(w, v.w, acc.w);
    }
#pragma unroll
    for (int m = 4; m <= 32; m <<= 1) {
        acc.x += __shfl_xor(acc.x, m); acc.y += __shfl_xor(acc.y, m);
        acc.z += __shfl_xor(acc.z, m); acc.w += __shfl_xor(acc.w, m);
    }
    if (g == 0) {
        float ri = r_in[n];
        float4 bb = *(const float4*)&b2[f * 4];
        float4 o;
        o.x = fmaf(acc.x, ri, bb.x); o.y = fmaf(acc.y, ri, bb.y);
        o.z = fmaf(acc.z, ri, bb.z); o.w = fmaf(acc.w, ri, bb.w);
        *(float4*)&out[(size_t)n * 16 + f * 4] = o;
    }
}

extern "C" void kernel_launch(void* const* d_in, const int* in_sizes, int n_in,
                              void* d_out, int out_size, void* d_ws, size_t ws_size,
                              hipStream_t stream) {
    const float* feats = (const float*)d_in[0];
    const int* src = (const int*)d_in[1];
    const int* dst = (const int*)d_in[2];
    const float* W0 = (const float*)d_in[3];
    const float* b0 = (const float*)d_in[4];
    const float* W1 = (const float*)d_in[5];
    const float* b1 = (const float*)d_in[6];
    const float* W2 = (const float*)d_in[7];
    const float* b2 = (const float*)d_in[8];
    float* out = (float*)d_out;

    // ws (float units):
    //   r_out[NN] | r_in[NN] | row_start[NN+16] | csr[NE] |
    //   R1[32NN]  (E2[NE ints] then A[bf16 64NN] then G[bf16 64NN])
    //   R2[32NN]  (cnt_out[NN]+bucket_cnt[NBUCK] ints transient, then B[bf16 64NN])
    //   C[16NN] f32 | bucket_base[NBUCK+1] | bucket_cursor[NBUCK]
    float* ws = (float*)d_ws;
    float* r_out = ws;
    float* r_in = ws + NN;
    int* row_start = (int*)(ws + 2 * NN);
    int* csr = (int*)(ws + 3 * NN + 16);
    float* R1 = ws + 3 * NN + 16 + NE;
    float* R2 = R1 + (size_t)32 * NN;
    float* C = R2 + (size_t)32 * NN;
    int* bucket_base = (int*)(C + (size_t)16 * NN);  // NBUCK+1
    int* bucket_cursor = bucket_base + NBUCK + 1;    // NBUCK

    int* E2 = (int*)R1;
    unsigned short* A = (unsigned short*)R1;  // after bcsr (E2 dead)
    unsigned short* G = A;                    // after gather<0> (A dead)
    int* cnt_out = (int*)R2;                  // transient, dead after k_rout
    int* bucket_cnt = cnt_out + NN;
    unsigned short* B = (unsigned short*)R2;  // after k_rout

    // build
    hipMemsetAsync(cnt_out, 0, (NN + NBUCK) * sizeof(int), stream);
    k_hist<<<256, 256, 0, stream>>>(src, dst, cnt_out, bucket_cnt);
    k_bscan<<<1, 1024, 0, stream>>>(bucket_cnt, bucket_base, bucket_cursor);
    k_pairs<<<(NE + PCHUNK - 1) / PCHUNK, 256, 0, stream>>>(src, dst, bucket_cursor, E2);
    k_bcsr<<<NBUCK, 256, 0, stream>>>(E2, bucket_base, row_start, r_in, csr);
    k_rout<<<(NN + 255) / 256, 256, 0, stream>>>(cnt_out, r_out);

    // layer 0
    k_gemm0<<<(NN + 63) / 64, 256, 0, stream>>>(feats, W0, r_out, A);
    k_gather64<0><<<NN / 4, 256, 0, stream>>>(row_start, csr, A, r_in, r_out, b0, B);

    // layer 1 (+ layer2 pre-GEMM)
    k_gather64<1><<<NN / 4, 256, 0, stream>>>(row_start, csr, B, r_in, r_out, b0, G);
    k_mlp<<<(NN + 63) / 64, 256, 0, stream>>>(G, W1, b1, W2, r_out, C);

    // layer 2
    k_gather16<<<NN / 4, 256, 0, stream>>>(row_start, csr, C, r_in, b2, out);
}